// Round 21
// baseline (77.022 us; speedup 1.0000x reference)
//
#include <hip/hip_runtime.h>
#include <hip/hip_bf16.h>
#include <math.h>

#define BB 32
#define NCTX 512
#define NAG 64
#define DD 256
#define TT 80
#define TEMB 64
#define NH 8
#define HD 32
#define MH 128

// d_out is FLOAT32: mask [0,163840) then emb [163840,819200).
// Validator bf16(RNE)-casts both sides. (Established rounds 0-8.)

typedef __attribute__((ext_vector_type(8))) short short8;
typedef __attribute__((ext_vector_type(4))) float f32x4;
typedef __attribute__((ext_vector_type(4))) unsigned short us4;

static __device__ inline ushort f2b(float f) {
  __hip_bfloat16 h = __float2bfloat16(f);
  return *reinterpret_cast<const ushort*>(&h);
}
static __device__ inline float b2f(ushort u) {
  __hip_bfloat16 h = *reinterpret_cast<const __hip_bfloat16*>(&u);
  return __bfloat162float(h);
}
static __device__ inline us4 pack4(float a, float b, float c, float d) {
  us4 r = {f2b(a), f2b(b), f2b(c), f2b(d)};
  return r;
}
static __device__ inline float rcpf(float x) { return __builtin_amdgcn_rcpf(x); }

#define OPART 655360   // floats per o-partial  (256 bh * 80 t * 32 d)
#define LPART 20480    // floats per l-partial  (256 bh * 80 t)

// ---- P: qproj-MFMA(4) | fusew(128) | agent-gemm(64) | KV proj (1024)
//  static LDS 31 KB (qproj: tw in 2 row-halves, Qs in 2 col-halves,
//  q_in held in registers between phases -- NO global roundtrip).
__global__ __launch_bounds__(256, 4) void k_P(
    const float* __restrict__ temb, const float* __restrict__ tw,
    const float* __restrict__ tb, const float* __restrict__ inw,
    const float* __restrict__ inb, const float* __restrict__ w1,
    const float* __restrict__ outw, const float* __restrict__ outb,
    const float* __restrict__ agent, const float* __restrict__ context,
    ushort* __restrict__ qb, ushort* __restrict__ wfb, float* __restrict__ bf,
    ushort* __restrict__ agentpb,
    ushort* __restrict__ kb, ushort* __restrict__ vb) {
  __shared__ __align__(16) char sm[30976];
  const int blk = blockIdx.x;
  const int tid = threadIdx.x;
  const int w = tid >> 6, lane = tid & 63;
  const int lgrp = lane >> 4, lcol = lane & 15;
  const int kgrp = lgrp << 3;
  f32x4 zero = {0.f, 0.f, 0.f, 0.f};

  if (blk < 4) {
    // ---- qproj. Phase 1: q_in = temb@tw^T (acc in regs), tw in 2 halves.
    ushort (*Tb)[72]   = (ushort(*)[72])sm;             // [80][72]  11520
    ushort (*Twin)[72] = (ushort(*)[72])(sm + 11520);   // [128][72] 18432
    ushort (*Qs)[136]  = (ushort(*)[136])sm;            // [80][136] 21760 (alias)
    ushort (*Bq)[72]   = (ushort(*)[72])(sm + 21760);   // [64][72]   9216
    #pragma unroll
    for (int l = 0; l < 5; ++l) {
      int e4 = tid + 256 * l;
      if (e4 < 1280) {
        int t = e4 >> 4, k4 = (e4 & 15) << 2;
        float4 v = *(const float4*)&temb[t * TEMB + k4];
        *(us4*)&Tb[t][k4] = pack4(v.x, v.y, v.z, v.w);
      }
    }
    f32x4 qin[2][5][2];
    #pragma unroll
    for (int hf = 0; hf < 2; ++hf)
      #pragma unroll
      for (int mt = 0; mt < 5; ++mt)
        #pragma unroll
        for (int nt = 0; nt < 2; ++nt) qin[hf][mt][nt] = zero;
    for (int hf = 0; hf < 2; ++hf) {
      __syncthreads();   // Tb staged (hf=0) / prior Twin reads done (hf=1)
      #pragma unroll
      for (int l = 0; l < 8; ++l) {
        int e4 = tid + 256 * l;      // 2048 quads
        int r = e4 >> 4, k4 = (e4 & 15) << 2;
        float4 v = *(const float4*)&tw[(size_t)((hf << 7) + r) * TEMB + k4];
        *(us4*)&Twin[r][k4] = pack4(v.x, v.y, v.z, v.w);
      }
      __syncthreads();
      #pragma unroll
      for (int ks = 0; ks < 2; ++ks) {
        #pragma unroll
        for (int mt = 0; mt < 5; ++mt) {
          short8 af = *(const short8*)&Tb[(mt << 4) + lcol][(ks << 5) + kgrp];
          #pragma unroll
          for (int nt = 0; nt < 2; ++nt) {
            short8 bfr = *(const short8*)&Twin[(w << 5) + (nt << 4) + lcol][(ks << 5) + kgrp];
            qin[hf][mt][nt] = __builtin_amdgcn_mfma_f32_16x16x32_bf16(af, bfr, qin[hf][mt][nt], 0, 0, 0);
          }
        }
      }
    }
    // Phase 2: q = q_in@wq^T + bq, scaled; Qs written per 128-col half.
    const int n0q = blk << 6;
    f32x4 acc2[5] = {zero, zero, zero, zero, zero};
    for (int kh = 0; kh < 2; ++kh) {
      __syncthreads();   // phase-1 LDS reads done / prior Qs+Bq reads done
      #pragma unroll
      for (int nt = 0; nt < 2; ++nt) {
        int n = (kh << 7) + (w << 5) + (nt << 4) + lcol;
        float tbn = tb[n];
        int c = (w << 5) + (nt << 4) + lcol;
        #pragma unroll
        for (int mt = 0; mt < 5; ++mt)
          #pragma unroll
          for (int r = 0; r < 4; ++r)
            Qs[(mt << 4) + (lgrp << 2) + r][c] = f2b(qin[kh][mt][nt][r] + tbn);
      }
      __syncthreads();
      for (int kc = 0; kc < 2; ++kc) {
        #pragma unroll
        for (int l = 0; l < 4; ++l) {
          int e4 = tid + 256 * l;    // 1024 quads
          int n = e4 >> 4, k4 = (e4 & 15) << 2;
          float4 v = *(const float4*)&inw[(size_t)(n0q + n) * DD + (kh << 7) + (kc << 6) + k4];
          *(us4*)&Bq[n][k4] = pack4(v.x, v.y, v.z, v.w);
        }
        __syncthreads();
        #pragma unroll
        for (int ks = 0; ks < 2; ++ks) {
          short8 bfr = *(const short8*)&Bq[(w << 4) + lcol][(ks << 5) + kgrp];
          #pragma unroll
          for (int mt = 0; mt < 5; ++mt) {
            short8 af = *(const short8*)&Qs[(mt << 4) + lcol][(kc << 6) + (ks << 5) + kgrp];
            acc2[mt] = __builtin_amdgcn_mfma_f32_16x16x32_bf16(af, bfr, acc2[mt], 0, 0, 0);
          }
        }
        __syncthreads();   // Bq reuse
      }
    }
    int n = n0q + (w << 4) + lcol;
    float bn = inb[n];
    #pragma unroll
    for (int mt = 0; mt < 5; ++mt)
      #pragma unroll
      for (int r = 0; r < 4; ++r) {
        int m = (mt << 4) + (lgrp << 2) + r;
        qb[m * DD + n] = f2b((acc2[mt][r] + bn) * 0.17677669529663687f);
      }
  } else if (blk < 132) {
    int i = blk - 4, j = tid;
    float* w1row = (float*)sm;
    float* red   = (float*)(sm + 1024);
    w1row[j] = w1[i * 2 * DD + DD + j];
    __syncthreads();
    float acc = 0.f;
    for (int k = 0; k < DD; ++k) acc += w1row[k] * outw[k * DD + j];
    wfb[i * DD + j] = f2b(acc);
    red[j] = w1row[j] * outb[j];
    __syncthreads();
    for (int s2 = 128; s2 > 0; s2 >>= 1) {
      if (j < s2) red[j] += red[j + s2];
      __syncthreads();
    }
    if (j == 0) bf[i] = red[0];
  } else if (blk < 196) {
    // agent projection: dual fp32-staged 64x64 GEMM, out bf16 agentpb
    int gb = blk - 132;
    const int m0 = (gb >> 1) << 6;
    const int n0 = (gb & 1) << 6;
    ushort (*Ab)[72] = (ushort(*)[72])sm;
    ushort (*Bb)[72] = (ushort(*)[72])(sm + 9216);
    f32x4 acc[4] = {zero, zero, zero, zero};
    for (int k0 = 0; k0 < 256; k0 += 64) {
      __syncthreads();
      #pragma unroll
      for (int l = 0; l < 4; ++l) {
        int e = tid + 256 * l;
        int m = e >> 4, k4 = (e & 15) << 2;
        float4 va = *(const float4*)&agent[(size_t)(m0 + m) * 256 + k0 + k4];
        *(us4*)&Ab[m][k4] = pack4(va.x, va.y, va.z, va.w);
        float4 vb2 = *(const float4*)&w1[(size_t)(n0 + m) * 512 + k0 + k4];
        *(us4*)&Bb[m][k4] = pack4(vb2.x, vb2.y, vb2.z, vb2.w);
      }
      __syncthreads();
      #pragma unroll
      for (int kk = 0; kk < 64; kk += 32) {
        short8 af = *(const short8*)&Ab[(w << 4) + lcol][kk + kgrp];
        #pragma unroll
        for (int tc = 0; tc < 4; ++tc) {
          short8 bfr = *(const short8*)&Bb[(tc << 4) + lcol][kk + kgrp];
          acc[tc] = __builtin_amdgcn_mfma_f32_16x16x32_bf16(af, bfr, acc[tc], 0, 0, 0);
        }
      }
    }
    #pragma unroll
    for (int tc = 0; tc < 4; ++tc) {
      int n = n0 + (tc << 4) + lcol;
      #pragma unroll
      for (int r = 0; r < 4; ++r) {
        int m = m0 + (w << 4) + (lgrp << 2) + r;
        agentpb[(size_t)m * MH + n] = f2b(acc[tc][r]);
      }
    }
  } else {
    // KV proj: 64(M) x 128(N) tile, fp32 inputs, pack staging.
    int kb2 = blk - 196;
    const int m0 = (kb2 & 255) << 6;
    const int n0 = (kb2 >> 8) << 7;
    ushort (*Ab)[72] = (ushort(*)[72])sm;
    ushort (*Bb)[72] = (ushort(*)[72])(sm + 9216);
    const float* Wm = inw + 256 * 256;
    const float* bkv = inb + 256;
    f32x4 acc[8];
    #pragma unroll
    for (int tc = 0; tc < 8; ++tc) acc[tc] = zero;
    for (int k0 = 0; k0 < 256; k0 += 64) {
      __syncthreads();
      #pragma unroll
      for (int l = 0; l < 4; ++l) {
        int e = tid + 256 * l;
        int m = e >> 4, k4 = (e & 15) << 2;
        float4 v = *(const float4*)&context[(size_t)(m0 + m) * 256 + k0 + k4];
        *(us4*)&Ab[m][k4] = pack4(v.x, v.y, v.z, v.w);
      }
      #pragma unroll
      for (int l = 0; l < 8; ++l) {
        int e = tid + 256 * l;
        int n = e >> 4, k4 = (e & 15) << 2;
        float4 v = *(const float4*)&Wm[(size_t)(n0 + n) * 256 + k0 + k4];
        *(us4*)&Bb[n][k4] = pack4(v.x, v.y, v.z, v.w);
      }
      __syncthreads();
      #pragma unroll
      for (int kk = 0; kk < 64; kk += 32) {
        short8 af = *(const short8*)&Ab[(w << 4) + lcol][kk + kgrp];
        #pragma unroll
        for (int tc = 0; tc < 8; ++tc) {
          short8 bfr = *(const short8*)&Bb[(tc << 4) + lcol][kk + kgrp];
          acc[tc] = __builtin_amdgcn_mfma_f32_16x16x32_bf16(af, bfr, acc[tc], 0, 0, 0);
        }
      }
    }
    #pragma unroll
    for (int tc = 0; tc < 8; ++tc) {
      int n = n0 + (tc << 4) + lcol;
      float bias = bkv[n];
      int h = (n >> 5) & 7, hd = n & 31;
      #pragma unroll
      for (int r = 0; r < 4; ++r) {
        int m = m0 + (w << 4) + (lgrp << 2) + r;
        int bl = m >> 9, s = m & 511;
        ushort v = f2b(acc[tc][r] + bias);
        if (n < 256)
          kb[(((size_t)(bl * NH + h)) * NCTX + s) * HD + hd] = v;
        else
          vb[(((size_t)(bl * NH + h)) * HD + hd) * NCTX + s] = v;
      }
    }
  }
}

// ---- B: attention halves. 512 blocks. XCD-paired mapping: part = blk>>8,
// bhl = blk&255 so the two partials of one (b,h) land on the SAME XCD
// (256 % 8 == 0) and the second K/V read is an L2 hit.
__global__ __launch_bounds__(256) void k_B(
    const ushort* __restrict__ qb, const ushort* __restrict__ kg,
    const ushort* __restrict__ vtg, float* __restrict__ oP,
    float* __restrict__ lP) {
  __shared__ __align__(16) char sm[47104];
  ushort (*Qb)[40]  = (ushort(*)[40])(sm);
  ushort (*Kb)[40]  = (ushort(*)[40])(sm + 6400);
  ushort (*Vb)[136] = (ushort(*)[136])(sm + 16640);
  ushort (*Pb)[136] = (ushort(*)[136])(sm + 25344);
  float  (*Ored)[80][32] = (float(*)[80][32])(sm);
  float  (*lred)[80] = (float(*)[80])(sm + 40960);
  const int blk = blockIdx.x;
  const int bhl = blk & 255, part = blk >> 8;
  const int h = bhl & 7;
  const int tid = threadIdx.x;
  const int w = tid >> 6, lane = tid & 63;
  const int lgrp = lane >> 4, lcol = lane & 15;
  const int kgrp = lgrp << 3;
  const ushort* kp = kg + (size_t)bhl * NCTX * HD;
  const ushort* vp = vtg + (size_t)bhl * HD * NCTX;
  #pragma unroll
  for (int l = 0; l < 2; ++l) {
    int e = tid + 256 * l;        // 320 short8 copies of Q (bf16 in global)
    if (e < 320) {
      int t = e >> 2, d8 = (e & 3) << 3;
      *(short8*)&Qb[t][d8] = *(const short8*)&qb[t * DD + h * HD + d8];
    }
  }
  f32x4 zero = {0.f, 0.f, 0.f, 0.f};
  f32x4 oacc[5][2];
  #pragma unroll
  for (int tt = 0; tt < 5; ++tt) { oacc[tt][0] = zero; oacc[tt][1] = zero; }
  float lpart[5] = {0.f, 0.f, 0.f, 0.f, 0.f};
  for (int c = 0; c < 2; ++c) {
    const int s0 = part * 256 + c * 128;
    __syncthreads();
    #pragma unroll
    for (int l = 0; l < 2; ++l) {
      int e = tid + 256 * l;
      int sl = e >> 2, d8 = (e & 3) << 3;
      *(short8*)&Kb[sl][d8] = *(const short8*)&kp[(size_t)(s0 + sl) * HD + d8];
      int d = e >> 4, s8 = (e & 15) << 3;
      *(short8*)&Vb[d][s8] = *(const short8*)&vp[(size_t)d * NCTX + s0 + s8];
    }
    __syncthreads();
    f32x4 sacc[2][5];
    #pragma unroll
    for (int st = 0; st < 2; ++st) {
      short8 af = *(const short8*)&Kb[(w << 5) + (st << 4) + lcol][kgrp];
      #pragma unroll
      for (int tt = 0; tt < 5; ++tt) {
        short8 bfr = *(const short8*)&Qb[(tt << 4) + lcol][kgrp];
        sacc[st][tt] = __builtin_amdgcn_mfma_f32_16x16x32_bf16(af, bfr, zero, 0, 0, 0);
      }
    }
    #pragma unroll
    for (int st = 0; st < 2; ++st) {
      #pragma unroll
      for (int tt = 0; tt < 5; ++tt) {
        float p0 = __expf(sacc[st][tt][0]), p1 = __expf(sacc[st][tt][1]);
        float p2 = __expf(sacc[st][tt][2]), p3 = __expf(sacc[st][tt][3]);
        ushort u0 = f2b(p0), u1 = f2b(p1), u2 = f2b(p2), u3 = f2b(p3);
        lpart[tt] += b2f(u0) + b2f(u1) + b2f(u2) + b2f(u3);
        uint2 pk;
        pk.x = (uint)u0 | ((uint)u1 << 16);
        pk.y = (uint)u2 | ((uint)u3 << 16);
        *(uint2*)&Pb[(tt << 4) + lcol][(w << 5) + (st << 4) + (lgrp << 2)] = pk;
      }
    }
    __syncthreads();
    #pragma unroll
    for (int tt = 0; tt < 5; ++tt) {
      short8 pa = *(const short8*)&Pb[(tt << 4) + lcol][(w << 5) + kgrp];
      #pragma unroll
      for (int dt = 0; dt < 2; ++dt) {
        short8 vbr = *(const short8*)&Vb[(dt << 4) + lcol][(w << 5) + kgrp];
        oacc[tt][dt] = __builtin_amdgcn_mfma_f32_16x16x32_bf16(pa, vbr, oacc[tt][dt], 0, 0, 0);
      }
    }
  }
  __syncthreads();
  #pragma unroll
  for (int tt = 0; tt < 5; ++tt) {
    float l = lpart[tt];
    l += __shfl_xor(l, 16); l += __shfl_xor(l, 32);
    if (lane < 16) lred[w][(tt << 4) + lane] = l;
    #pragma unroll
    for (int dt = 0; dt < 2; ++dt)
      #pragma unroll
      for (int r = 0; r < 4; ++r)
        Ored[w][(tt << 4) + (lgrp << 2) + r][(dt << 4) + lcol] = oacc[tt][dt][r];
  }
  __syncthreads();
  float* op = oP + (size_t)part * OPART + (size_t)bhl * TT * HD;
  for (int i = tid; i < TT * HD; i += 256) {
    int t = i >> 5, d = i & 31;
    op[i] = Ored[0][t][d] + Ored[1][t][d] + Ored[2][t][d] + Ored[3][t][d];
  }
  for (int t = tid; t < TT; t += 256)
    lP[(size_t)part * LPART + (size_t)bhl * TT + t] =
        lred[0][t] + lred[1][t] + lred[2][t] + lred[3][t];
}

// ---- C: combine attention partials + attn-out projection (80 blocks)
__global__ __launch_bounds__(256) void k_C(
    const float* __restrict__ oP, const float* __restrict__ lP,
    const ushort* __restrict__ wfb, const float* __restrict__ bfv,
    ushort* __restrict__ attnpb) {
  __shared__ __align__(16) ushort Ab[64][72];
  const int gb = blockIdx.x;
  const int m0 = (gb >> 1) << 6;
  const int n0 = (gb & 1) << 6;
  const int tid = threadIdx.x;
  const int w = tid >> 6, lane = tid & 63;
  const int lgrp = lane >> 4, lcol = lane & 15;
  const int kgrp = lgrp << 3;
  f32x4 zero = {0.f, 0.f, 0.f, 0.f};
  f32x4 acc[4] = {zero, zero, zero, zero};
  for (int k0 = 0; k0 < 256; k0 += 64) {
    __syncthreads();
    #pragma unroll
    for (int l = 0; l < 4; ++l) {
      int e = tid + 256 * l;
      int m = e >> 4, c4 = (e & 15) << 2;
      int row = m0 + m;
      int bg = row / 80, t = row - bg * 80;
      int dfull = k0 + c4, h = dfull >> 5, hd = dfull & 31;
      size_t bh = (size_t)(bg * NH + h);
      const float* o0 = &oP[(bh * TT + t) * HD + hd];
      float4 a0 = *(const float4*)o0;
      float4 a1 = *(const float4*)(o0 + OPART);
      float li = rcpf(lP[bh * TT + t] + lP[LPART + bh * TT + t]);
      *(us4*)&Ab[m][c4] = pack4((a0.x + a1.x) * li, (a0.y + a1.y) * li,
                                (a0.z + a1.z) * li, (a0.w + a1.w) * li);
    }
    __syncthreads();
    #pragma unroll
    for (int kk = 0; kk < 64; kk += 32) {
      short8 af = *(const short8*)&Ab[(w << 4) + lcol][kk + kgrp];
      #pragma unroll
      for (int tc = 0; tc < 4; ++tc) {
        short8 bfr = *(const short8*)&wfb[(size_t)(n0 + (tc << 4) + lcol) * 256 + k0 + kk + kgrp];
        acc[tc] = __builtin_amdgcn_mfma_f32_16x16x32_bf16(af, bfr, acc[tc], 0, 0, 0);
      }
    }
  }
  #pragma unroll
  for (int tc = 0; tc < 4; ++tc) {
    int n = n0 + (tc << 4) + lcol;
    float bv = bfv[n];
    #pragma unroll
    for (int r = 0; r < 4; ++r) {
      int m = m0 + (w << 4) + (lgrp << 2) + r;
      attnpb[(size_t)m * MH + n] = f2b(acc[tc][r] + bv);
    }
  }
}

// ---- D: fused MLP. 4 token-tiles (2a x 2t) per block reusing staged W2.
__global__ __launch_bounds__(256) void k_D(
    const ushort* __restrict__ agentpb, const ushort* __restrict__ attnpb,
    const float* __restrict__ w2, const float* __restrict__ b1g,
    const float* __restrict__ b2g, const float* __restrict__ w3,
    const float* __restrict__ b3, const float* __restrict__ mew,
    const float* __restrict__ meb, const float* __restrict__ esc,
    float* __restrict__ mask_out, float* __restrict__ emb_out) {
  const int b = blockIdx.z;
  const int tid = threadIdx.x;
  __shared__ ushort Xb[64][136];
  __shared__ ushort Wb[128][136];
  #pragma unroll
  for (int l = 0; l < 16; ++l) {
    int e4 = tid + 256 * l;
    int o = e4 >> 5, k4 = (e4 & 31) << 2;
    float4 v = *(const float4*)&w2[(size_t)o * MH + k4];
    *(us4*)&Wb[o][k4] = pack4(v.x, v.y, v.z, v.w);
  }
  const int w = tid >> 6, lane = tid & 63;
  const int lgrp = lane >> 4, lcol = lane & 15;
  const int kgrp = lgrp << 3;
  f32x4 zero = {0.f, 0.f, 0.f, 0.f};
  float es = esc[0], b3v = b3[0];
  float m0 = mew[0], m1 = mew[1], m2 = mew[2], m3 = mew[3];
  float e0 = meb[0], e1 = meb[1], e2 = meb[2], e3 = meb[3];
  for (int rep = 0; rep < 4; ++rep) {
    const int t0 = blockIdx.x * 16 + (rep >> 1) * 8;
    const int a0 = blockIdx.y * 16 + (rep & 1) * 8;
    __syncthreads();   // Wb ready (rep0) / previous Xb reads done (rep>0)
    #pragma unroll
    for (int l = 0; l < 8; ++l) {
      int e4 = tid + 256 * l;
      int tok = e4 >> 5, k4 = (e4 & 31) << 2;
      int a = a0 + (tok >> 3), t = t0 + (tok & 7);
      us4 au = *(const us4*)&agentpb[((size_t)b * NAG + a) * MH + k4];
      us4 tu = *(const us4*)&attnpb[((size_t)b * TT + t) * MH + k4];
      float4 bb = *(const float4*)&b1g[k4];
      float x0 = b2f(au[0]) + b2f(tu[0]) + bb.x;
      float x1 = b2f(au[1]) + b2f(tu[1]) + bb.y;
      float x2 = b2f(au[2]) + b2f(tu[2]) + bb.z;
      float x3 = b2f(au[3]) + b2f(tu[3]) + bb.w;
      *(us4*)&Xb[tok][k4] = pack4(x0 * rcpf(1.f + __expf(-x0)),
                                  x1 * rcpf(1.f + __expf(-x1)),
                                  x2 * rcpf(1.f + __expf(-x2)),
                                  x3 * rcpf(1.f + __expf(-x3)));
    }
    __syncthreads();
    f32x4 acc[8] = {zero, zero, zero, zero, zero, zero, zero, zero};
    #pragma unroll
    for (int k0 = 0; k0 < MH; k0 += 32) {
      short8 af = *(const short8*)&Xb[(w << 4) + lcol][k0 + kgrp];
      #pragma unroll
      for (int tc = 0; tc < 8; ++tc) {
        short8 bfr = *(const short8*)&Wb[(tc << 4) + lcol][k0 + kgrp];
        acc[tc] = __builtin_amdgcn_mfma_f32_16x16x32_bf16(af, bfr, acc[tc], 0, 0, 0);
      }
    }
    float psum[4] = {0.f, 0.f, 0.f, 0.f};
    #pragma unroll
    for (int tc = 0; tc < 8; ++tc) {
      int o = (tc << 4) + lcol;
      float b2o = b2g[o], w3o = w3[o];
      #pragma unroll
      for (int r = 0; r < 4; ++r) {
        float hv = acc[tc][r] + b2o;
        hv = hv * rcpf(1.f + __expf(-hv));
        psum[r] += hv * w3o;
      }
    }
    #pragma unroll
    for (int r = 0; r < 4; ++r) {
      float p = psum[r];
      p += __shfl_xor(p, 1); p += __shfl_xor(p, 2);
      p += __shfl_xor(p, 4); p += __shfl_xor(p, 8);
      if (lcol == 0) {
        int tok = (w << 4) + (lgrp << 2) + r;
        int a = a0 + (tok >> 3), t = t0 + (tok & 7);
        float mask = rcpf(1.f + __expf(-(p + b3v)));
        size_t mi = ((size_t)b * NAG + a) * TT + t;
        mask_out[mi] = mask;
        emb_out[mi * 4 + 0] = (mask * m0 + e0) * es;
        emb_out[mi * 4 + 1] = (mask * m1 + e1) * es;
        emb_out[mi * 4 + 2] = (mask * m2 + e2) * es;
        emb_out[mi * 4 + 3] = (mask * m3 + e3) * es;
      }
    }
  }
}

extern "C" void kernel_launch(void* const* d_in, const int* in_sizes, int n_in,
                              void* d_out, int out_size, void* d_ws, size_t ws_size,
                              hipStream_t stream) {
  const float* context = (const float*)d_in[0];
  const float* agent   = (const float*)d_in[1];
  const float* temb    = (const float*)d_in[2];
  const float* tw      = (const float*)d_in[3];
  const float* tb      = (const float*)d_in[4];
  const float* inw     = (const float*)d_in[5];
  const float* inb     = (const float*)d_in[6];
  const float* outw    = (const float*)d_in[7];
  const float* outb    = (const float*)d_in[8];
  const float* w1      = (const float*)d_in[9];
  const float* b1      = (const float*)d_in[10];
  const float* w2      = (const float*)d_in[11];
  const float* b2      = (const float*)d_in[12];
  const float* w3      = (const float*)d_in[13];
  const float* b3      = (const float*)d_in[14];
  const float* mew     = (const float*)d_in[15];
  const float* meb     = (const float*)d_in[16];
  const float* esc     = (const float*)d_in[17];

  float* ws = (float*)d_ws;
  float* bf  = ws + 0;                 // 128
  float* oP  = ws + 128;               // 2*655360
  float* lP  = ws + 1310848;           // 2*20480
  ushort* u16 = (ushort*)(ws + 1351808);
  ushort* wfb     = u16;               // 32768
  ushort* agentpb = u16 + 32768;       // 262144
  ushort* attnpb  = u16 + 294912;      // 327680
  ushort* kbufb   = u16 + 622592;      // 4194304
  ushort* vbufb   = u16 + 4816896;     // 4194304
  ushort* qb      = u16 + 9011200;     // 20480

  float* mask_out = (float*)d_out;
  float* emb_out  = mask_out + (size_t)BB * NAG * TT;

  k_P<<<dim3(196 + 1024), dim3(256), 0, stream>>>(
      temb, tw, tb, inw, inb, w1, outw, outb, agent, context,
      qb, wfb, bf, agentpb, kbufb, vbufb);
  k_B<<<dim3(512), dim3(256), 0, stream>>>(
      qb, kbufb, vbufb, oP, lP);
  k_C<<<dim3(80), dim3(256), 0, stream>>>(oP, lP, wfb, bf, attnpb);
  k_D<<<dim3(5, 4, 32), dim3(256), 0, stream>>>(
      agentpb, attnpb, w2, b1, b2, w3, b3, mew, meb, esc, mask_out, emb_out);
}

// Round 22
// 74.415 us; speedup vs baseline: 1.0350x; 1.0350x over previous
//
#include <hip/hip_runtime.h>
#include <hip/hip_bf16.h>
#include <math.h>

#define BB 32
#define NCTX 512
#define NAG 64
#define DD 256
#define TT 80
#define TEMB 64
#define NH 8
#define HD 32
#define MH 128

// d_out is FLOAT32: mask [0,163840) then emb [163840,819200).
// Validator bf16(RNE)-casts both sides. (Established rounds 0-8.)

typedef __attribute__((ext_vector_type(8))) short short8;
typedef __attribute__((ext_vector_type(4))) float f32x4;
typedef __attribute__((ext_vector_type(4))) unsigned short us4;

static __device__ inline ushort f2b(float f) {
  __hip_bfloat16 h = __float2bfloat16(f);
  return *reinterpret_cast<const ushort*>(&h);
}
static __device__ inline float b2f(ushort u) {
  __hip_bfloat16 h = *reinterpret_cast<const __hip_bfloat16*>(&u);
  return __bfloat162float(h);
}
static __device__ inline us4 pack4(float a, float b, float c, float d) {
  us4 r = {f2b(a), f2b(b), f2b(c), f2b(d)};
  return r;
}
static __device__ inline float rcpf(float x) { return __builtin_amdgcn_rcpf(x); }

#define OPART 655360   // floats per o-partial  (256 bh * 80 t * 32 d)
#define LPART 20480    // floats per l-partial  (256 bh * 80 t)

// ---- P: qproj-MFMA(4) | fusew(128) | agent-gemm(64) | KV proj (1024)
//  static LDS 31 KB (qproj: tw in 2 row-halves, Qs in 2 col-halves,
//  q_in held in registers between phases -- NO global roundtrip).
__global__ __launch_bounds__(256, 4) void k_P(
    const float* __restrict__ temb, const float* __restrict__ tw,
    const float* __restrict__ tb, const float* __restrict__ inw,
    const float* __restrict__ inb, const float* __restrict__ w1,
    const float* __restrict__ outw, const float* __restrict__ outb,
    const float* __restrict__ agent, const float* __restrict__ context,
    ushort* __restrict__ qb, ushort* __restrict__ wfb, float* __restrict__ bf,
    ushort* __restrict__ agentpb,
    ushort* __restrict__ kb, ushort* __restrict__ vb) {
  __shared__ __align__(16) char sm[30976];
  const int blk = blockIdx.x;
  const int tid = threadIdx.x;
  const int w = tid >> 6, lane = tid & 63;
  const int lgrp = lane >> 4, lcol = lane & 15;
  const int kgrp = lgrp << 3;
  f32x4 zero = {0.f, 0.f, 0.f, 0.f};

  if (blk < 4) {
    // ---- qproj. Phase 1: q_in = temb@tw^T (acc in regs), tw in 2 halves.
    ushort (*Tb)[72]   = (ushort(*)[72])sm;             // [80][72]  11520
    ushort (*Twin)[72] = (ushort(*)[72])(sm + 11520);   // [128][72] 18432
    ushort (*Qs)[136]  = (ushort(*)[136])sm;            // [80][136] 21760 (alias)
    ushort (*Bq)[72]   = (ushort(*)[72])(sm + 21760);   // [64][72]   9216
    #pragma unroll
    for (int l = 0; l < 5; ++l) {
      int e4 = tid + 256 * l;
      if (e4 < 1280) {
        int t = e4 >> 4, k4 = (e4 & 15) << 2;
        float4 v = *(const float4*)&temb[t * TEMB + k4];
        *(us4*)&Tb[t][k4] = pack4(v.x, v.y, v.z, v.w);
      }
    }
    f32x4 qin[2][5][2];
    #pragma unroll
    for (int hf = 0; hf < 2; ++hf)
      #pragma unroll
      for (int mt = 0; mt < 5; ++mt)
        #pragma unroll
        for (int nt = 0; nt < 2; ++nt) qin[hf][mt][nt] = zero;
    for (int hf = 0; hf < 2; ++hf) {
      __syncthreads();   // Tb staged (hf=0) / prior Twin reads done (hf=1)
      #pragma unroll
      for (int l = 0; l < 8; ++l) {
        int e4 = tid + 256 * l;      // 2048 quads
        int r = e4 >> 4, k4 = (e4 & 15) << 2;
        float4 v = *(const float4*)&tw[(size_t)((hf << 7) + r) * TEMB + k4];
        *(us4*)&Twin[r][k4] = pack4(v.x, v.y, v.z, v.w);
      }
      __syncthreads();
      #pragma unroll
      for (int ks = 0; ks < 2; ++ks) {
        #pragma unroll
        for (int mt = 0; mt < 5; ++mt) {
          short8 af = *(const short8*)&Tb[(mt << 4) + lcol][(ks << 5) + kgrp];
          #pragma unroll
          for (int nt = 0; nt < 2; ++nt) {
            short8 bfr = *(const short8*)&Twin[(w << 5) + (nt << 4) + lcol][(ks << 5) + kgrp];
            qin[hf][mt][nt] = __builtin_amdgcn_mfma_f32_16x16x32_bf16(af, bfr, qin[hf][mt][nt], 0, 0, 0);
          }
        }
      }
    }
    // Phase 2: q = q_in@wq^T + bq, scaled; Qs written per 128-col half.
    const int n0q = blk << 6;
    f32x4 acc2[5] = {zero, zero, zero, zero, zero};
    for (int kh = 0; kh < 2; ++kh) {
      __syncthreads();   // phase-1 LDS reads done / prior Qs+Bq reads done
      #pragma unroll
      for (int nt = 0; nt < 2; ++nt) {
        int n = (kh << 7) + (w << 5) + (nt << 4) + lcol;
        float tbn = tb[n];
        int c = (w << 5) + (nt << 4) + lcol;
        #pragma unroll
        for (int mt = 0; mt < 5; ++mt)
          #pragma unroll
          for (int r = 0; r < 4; ++r)
            Qs[(mt << 4) + (lgrp << 2) + r][c] = f2b(qin[kh][mt][nt][r] + tbn);
      }
      __syncthreads();
      for (int kc = 0; kc < 2; ++kc) {
        #pragma unroll
        for (int l = 0; l < 4; ++l) {
          int e4 = tid + 256 * l;    // 1024 quads
          int n = e4 >> 4, k4 = (e4 & 15) << 2;
          float4 v = *(const float4*)&inw[(size_t)(n0q + n) * DD + (kh << 7) + (kc << 6) + k4];
          *(us4*)&Bq[n][k4] = pack4(v.x, v.y, v.z, v.w);
        }
        __syncthreads();
        #pragma unroll
        for (int ks = 0; ks < 2; ++ks) {
          short8 bfr = *(const short8*)&Bq[(w << 4) + lcol][(ks << 5) + kgrp];
          #pragma unroll
          for (int mt = 0; mt < 5; ++mt) {
            short8 af = *(const short8*)&Qs[(mt << 4) + lcol][(kc << 6) + (ks << 5) + kgrp];
            acc2[mt] = __builtin_amdgcn_mfma_f32_16x16x32_bf16(af, bfr, acc2[mt], 0, 0, 0);
          }
        }
        __syncthreads();   // Bq reuse
      }
    }
    int n = n0q + (w << 4) + lcol;
    float bn = inb[n];
    #pragma unroll
    for (int mt = 0; mt < 5; ++mt)
      #pragma unroll
      for (int r = 0; r < 4; ++r) {
        int m = (mt << 4) + (lgrp << 2) + r;
        qb[m * DD + n] = f2b((acc2[mt][r] + bn) * 0.17677669529663687f);
      }
  } else if (blk < 132) {
    int i = blk - 4, j = tid;
    float* w1row = (float*)sm;
    float* red   = (float*)(sm + 1024);
    w1row[j] = w1[i * 2 * DD + DD + j];
    __syncthreads();
    float acc = 0.f;
    for (int k = 0; k < DD; ++k) acc += w1row[k] * outw[k * DD + j];
    wfb[i * DD + j] = f2b(acc);
    red[j] = w1row[j] * outb[j];
    __syncthreads();
    for (int s2 = 128; s2 > 0; s2 >>= 1) {
      if (j < s2) red[j] += red[j + s2];
      __syncthreads();
    }
    if (j == 0) bf[i] = red[0];
  } else if (blk < 196) {
    // agent projection: dual fp32-staged 64x64 GEMM, out bf16 agentpb
    int gb = blk - 132;
    const int m0 = (gb >> 1) << 6;
    const int n0 = (gb & 1) << 6;
    ushort (*Ab)[72] = (ushort(*)[72])sm;
    ushort (*Bb)[72] = (ushort(*)[72])(sm + 9216);
    f32x4 acc[4] = {zero, zero, zero, zero};
    for (int k0 = 0; k0 < 256; k0 += 64) {
      __syncthreads();
      #pragma unroll
      for (int l = 0; l < 4; ++l) {
        int e = tid + 256 * l;
        int m = e >> 4, k4 = (e & 15) << 2;
        float4 va = *(const float4*)&agent[(size_t)(m0 + m) * 256 + k0 + k4];
        *(us4*)&Ab[m][k4] = pack4(va.x, va.y, va.z, va.w);
        float4 vb2 = *(const float4*)&w1[(size_t)(n0 + m) * 512 + k0 + k4];
        *(us4*)&Bb[m][k4] = pack4(vb2.x, vb2.y, vb2.z, vb2.w);
      }
      __syncthreads();
      #pragma unroll
      for (int kk = 0; kk < 64; kk += 32) {
        short8 af = *(const short8*)&Ab[(w << 4) + lcol][kk + kgrp];
        #pragma unroll
        for (int tc = 0; tc < 4; ++tc) {
          short8 bfr = *(const short8*)&Bb[(tc << 4) + lcol][kk + kgrp];
          acc[tc] = __builtin_amdgcn_mfma_f32_16x16x32_bf16(af, bfr, acc[tc], 0, 0, 0);
        }
      }
    }
    #pragma unroll
    for (int tc = 0; tc < 4; ++tc) {
      int n = n0 + (tc << 4) + lcol;
      #pragma unroll
      for (int r = 0; r < 4; ++r) {
        int m = m0 + (w << 4) + (lgrp << 2) + r;
        agentpb[(size_t)m * MH + n] = f2b(acc[tc][r]);
      }
    }
  } else {
    // KV proj: 64(M) x 128(N) tile, fp32 inputs, pack staging.
    int kb2 = blk - 196;
    const int m0 = (kb2 & 255) << 6;
    const int n0 = (kb2 >> 8) << 7;
    ushort (*Ab)[72] = (ushort(*)[72])sm;
    ushort (*Bb)[72] = (ushort(*)[72])(sm + 9216);
    const float* Wm = inw + 256 * 256;
    const float* bkv = inb + 256;
    f32x4 acc[8];
    #pragma unroll
    for (int tc = 0; tc < 8; ++tc) acc[tc] = zero;
    for (int k0 = 0; k0 < 256; k0 += 64) {
      __syncthreads();
      #pragma unroll
      for (int l = 0; l < 4; ++l) {
        int e = tid + 256 * l;
        int m = e >> 4, k4 = (e & 15) << 2;
        float4 v = *(const float4*)&context[(size_t)(m0 + m) * 256 + k0 + k4];
        *(us4*)&Ab[m][k4] = pack4(v.x, v.y, v.z, v.w);
      }
      #pragma unroll
      for (int l = 0; l < 8; ++l) {
        int e = tid + 256 * l;
        int n = e >> 4, k4 = (e & 15) << 2;
        float4 v = *(const float4*)&Wm[(size_t)(n0 + n) * 256 + k0 + k4];
        *(us4*)&Bb[n][k4] = pack4(v.x, v.y, v.z, v.w);
      }
      __syncthreads();
      #pragma unroll
      for (int kk = 0; kk < 64; kk += 32) {
        short8 af = *(const short8*)&Ab[(w << 4) + lcol][kk + kgrp];
        #pragma unroll
        for (int tc = 0; tc < 8; ++tc) {
          short8 bfr = *(const short8*)&Bb[(tc << 4) + lcol][kk + kgrp];
          acc[tc] = __builtin_amdgcn_mfma_f32_16x16x32_bf16(af, bfr, acc[tc], 0, 0, 0);
        }
      }
    }
    #pragma unroll
    for (int tc = 0; tc < 8; ++tc) {
      int n = n0 + (tc << 4) + lcol;
      float bias = bkv[n];
      int h = (n >> 5) & 7, hd = n & 31;
      #pragma unroll
      for (int r = 0; r < 4; ++r) {
        int m = m0 + (w << 4) + (lgrp << 2) + r;
        int bl = m >> 9, s = m & 511;
        ushort v = f2b(acc[tc][r] + bias);
        if (n < 256)
          kb[(((size_t)(bl * NH + h)) * NCTX + s) * HD + hd] = v;
        else
          vb[(((size_t)(bl * NH + h)) * HD + hd) * NCTX + s] = v;
      }
    }
  }
}

// ---- B: attention halves. 512 blocks: (bh, part). Each does 256 s-positions
// (2 chunks of 128), writes PARTIAL o (fp32) and l to ws.
__global__ __launch_bounds__(256) void k_B(
    const ushort* __restrict__ qb, const ushort* __restrict__ kg,
    const ushort* __restrict__ vtg, float* __restrict__ oP,
    float* __restrict__ lP) {
  __shared__ __align__(16) char sm[47104];
  ushort (*Qb)[40]  = (ushort(*)[40])(sm);
  ushort (*Kb)[40]  = (ushort(*)[40])(sm + 6400);
  ushort (*Vb)[136] = (ushort(*)[136])(sm + 16640);
  ushort (*Pb)[136] = (ushort(*)[136])(sm + 25344);
  float  (*Ored)[80][32] = (float(*)[80][32])(sm);
  float  (*lred)[80] = (float(*)[80])(sm + 40960);
  const int blk = blockIdx.x;
  const int bhl = blk >> 1, part = blk & 1;
  const int h = bhl & 7;
  const int tid = threadIdx.x;
  const int w = tid >> 6, lane = tid & 63;
  const int lgrp = lane >> 4, lcol = lane & 15;
  const int kgrp = lgrp << 3;
  const ushort* kp = kg + (size_t)bhl * NCTX * HD;
  const ushort* vp = vtg + (size_t)bhl * HD * NCTX;
  #pragma unroll
  for (int l = 0; l < 2; ++l) {
    int e = tid + 256 * l;        // 320 short8 copies of Q (bf16 in global)
    if (e < 320) {
      int t = e >> 2, d8 = (e & 3) << 3;
      *(short8*)&Qb[t][d8] = *(const short8*)&qb[t * DD + h * HD + d8];
    }
  }
  f32x4 zero = {0.f, 0.f, 0.f, 0.f};
  f32x4 oacc[5][2];
  #pragma unroll
  for (int tt = 0; tt < 5; ++tt) { oacc[tt][0] = zero; oacc[tt][1] = zero; }
  float lpart[5] = {0.f, 0.f, 0.f, 0.f, 0.f};
  for (int c = 0; c < 2; ++c) {
    const int s0 = part * 256 + c * 128;
    __syncthreads();
    #pragma unroll
    for (int l = 0; l < 2; ++l) {
      int e = tid + 256 * l;
      int sl = e >> 2, d8 = (e & 3) << 3;
      *(short8*)&Kb[sl][d8] = *(const short8*)&kp[(size_t)(s0 + sl) * HD + d8];
      int d = e >> 4, s8 = (e & 15) << 3;
      *(short8*)&Vb[d][s8] = *(const short8*)&vp[(size_t)d * NCTX + s0 + s8];
    }
    __syncthreads();
    f32x4 sacc[2][5];
    #pragma unroll
    for (int st = 0; st < 2; ++st) {
      short8 af = *(const short8*)&Kb[(w << 5) + (st << 4) + lcol][kgrp];
      #pragma unroll
      for (int tt = 0; tt < 5; ++tt) {
        short8 bfr = *(const short8*)&Qb[(tt << 4) + lcol][kgrp];
        sacc[st][tt] = __builtin_amdgcn_mfma_f32_16x16x32_bf16(af, bfr, zero, 0, 0, 0);
      }
    }
    #pragma unroll
    for (int st = 0; st < 2; ++st) {
      #pragma unroll
      for (int tt = 0; tt < 5; ++tt) {
        float p0 = __expf(sacc[st][tt][0]), p1 = __expf(sacc[st][tt][1]);
        float p2 = __expf(sacc[st][tt][2]), p3 = __expf(sacc[st][tt][3]);
        ushort u0 = f2b(p0), u1 = f2b(p1), u2 = f2b(p2), u3 = f2b(p3);
        lpart[tt] += b2f(u0) + b2f(u1) + b2f(u2) + b2f(u3);
        uint2 pk;
        pk.x = (uint)u0 | ((uint)u1 << 16);
        pk.y = (uint)u2 | ((uint)u3 << 16);
        *(uint2*)&Pb[(tt << 4) + lcol][(w << 5) + (st << 4) + (lgrp << 2)] = pk;
      }
    }
    __syncthreads();
    #pragma unroll
    for (int tt = 0; tt < 5; ++tt) {
      short8 pa = *(const short8*)&Pb[(tt << 4) + lcol][(w << 5) + kgrp];
      #pragma unroll
      for (int dt = 0; dt < 2; ++dt) {
        short8 vbr = *(const short8*)&Vb[(dt << 4) + lcol][(w << 5) + kgrp];
        oacc[tt][dt] = __builtin_amdgcn_mfma_f32_16x16x32_bf16(pa, vbr, oacc[tt][dt], 0, 0, 0);
      }
    }
  }
  __syncthreads();
  #pragma unroll
  for (int tt = 0; tt < 5; ++tt) {
    float l = lpart[tt];
    l += __shfl_xor(l, 16); l += __shfl_xor(l, 32);
    if (lane < 16) lred[w][(tt << 4) + lane] = l;
    #pragma unroll
    for (int dt = 0; dt < 2; ++dt)
      #pragma unroll
      for (int r = 0; r < 4; ++r)
        Ored[w][(tt << 4) + (lgrp << 2) + r][(dt << 4) + lcol] = oacc[tt][dt][r];
  }
  __syncthreads();
  float* op = oP + (size_t)part * OPART + (size_t)bhl * TT * HD;
  for (int i = tid; i < TT * HD; i += 256) {
    int t = i >> 5, d = i & 31;
    op[i] = Ored[0][t][d] + Ored[1][t][d] + Ored[2][t][d] + Ored[3][t][d];
  }
  for (int t = tid; t < TT; t += 256)
    lP[(size_t)part * LPART + (size_t)bhl * TT + t] =
        lred[0][t] + lred[1][t] + lred[2][t] + lred[3][t];
}

// ---- C: combine attention partials + attn-out projection (80 blocks)
__global__ __launch_bounds__(256) void k_C(
    const float* __restrict__ oP, const float* __restrict__ lP,
    const ushort* __restrict__ wfb, const float* __restrict__ bfv,
    ushort* __restrict__ attnpb) {
  __shared__ __align__(16) ushort Ab[64][72];
  const int gb = blockIdx.x;
  const int m0 = (gb >> 1) << 6;
  const int n0 = (gb & 1) << 6;
  const int tid = threadIdx.x;
  const int w = tid >> 6, lane = tid & 63;
  const int lgrp = lane >> 4, lcol = lane & 15;
  const int kgrp = lgrp << 3;
  f32x4 zero = {0.f, 0.f, 0.f, 0.f};
  f32x4 acc[4] = {zero, zero, zero, zero};
  for (int k0 = 0; k0 < 256; k0 += 64) {
    __syncthreads();
    #pragma unroll
    for (int l = 0; l < 4; ++l) {
      int e = tid + 256 * l;
      int m = e >> 4, c4 = (e & 15) << 2;
      int row = m0 + m;
      int bg = row / 80, t = row - bg * 80;
      int dfull = k0 + c4, h = dfull >> 5, hd = dfull & 31;
      size_t bh = (size_t)(bg * NH + h);
      const float* o0 = &oP[(bh * TT + t) * HD + hd];
      float4 a0 = *(const float4*)o0;
      float4 a1 = *(const float4*)(o0 + OPART);
      float li = rcpf(lP[bh * TT + t] + lP[LPART + bh * TT + t]);
      *(us4*)&Ab[m][c4] = pack4((a0.x + a1.x) * li, (a0.y + a1.y) * li,
                                (a0.z + a1.z) * li, (a0.w + a1.w) * li);
    }
    __syncthreads();
    #pragma unroll
    for (int kk = 0; kk < 64; kk += 32) {
      short8 af = *(const short8*)&Ab[(w << 4) + lcol][kk + kgrp];
      #pragma unroll
      for (int tc = 0; tc < 4; ++tc) {
        short8 bfr = *(const short8*)&wfb[(size_t)(n0 + (tc << 4) + lcol) * 256 + k0 + kk + kgrp];
        acc[tc] = __builtin_amdgcn_mfma_f32_16x16x32_bf16(af, bfr, acc[tc], 0, 0, 0);
      }
    }
  }
  #pragma unroll
  for (int tc = 0; tc < 4; ++tc) {
    int n = n0 + (tc << 4) + lcol;
    float bv = bfv[n];
    #pragma unroll
    for (int r = 0; r < 4; ++r) {
      int m = m0 + (w << 4) + (lgrp << 2) + r;
      attnpb[(size_t)m * MH + n] = f2b(acc[tc][r] + bv);
    }
  }
}

// ---- D: fused MLP. 2 token-tiles per block reusing staged W2 (from fp32).
__global__ __launch_bounds__(256) void k_D(
    const ushort* __restrict__ agentpb, const ushort* __restrict__ attnpb,
    const float* __restrict__ w2, const float* __restrict__ b1g,
    const float* __restrict__ b2g, const float* __restrict__ w3,
    const float* __restrict__ b3, const float* __restrict__ mew,
    const float* __restrict__ meb, const float* __restrict__ esc,
    float* __restrict__ mask_out, float* __restrict__ emb_out) {
  const int a0 = blockIdx.y * 8;
  const int b = blockIdx.z;
  const int tid = threadIdx.x;
  __shared__ ushort Xb[64][136];
  __shared__ ushort Wb[128][136];
  #pragma unroll
  for (int l = 0; l < 16; ++l) {
    int e4 = tid + 256 * l;
    int o = e4 >> 5, k4 = (e4 & 31) << 2;
    float4 v = *(const float4*)&w2[(size_t)o * MH + k4];
    *(us4*)&Wb[o][k4] = pack4(v.x, v.y, v.z, v.w);
  }
  const int w = tid >> 6, lane = tid & 63;
  const int lgrp = lane >> 4, lcol = lane & 15;
  const int kgrp = lgrp << 3;
  f32x4 zero = {0.f, 0.f, 0.f, 0.f};
  float es = esc[0], b3v = b3[0];
  float m0 = mew[0], m1 = mew[1], m2 = mew[2], m3 = mew[3];
  float e0 = meb[0], e1 = meb[1], e2 = meb[2], e3 = meb[3];
  for (int rep = 0; rep < 2; ++rep) {
    const int t0 = blockIdx.x * 16 + rep * 8;
    __syncthreads();   // Wb ready (rep0) / previous Xb reads done (rep1)
    #pragma unroll
    for (int l = 0; l < 8; ++l) {
      int e4 = tid + 256 * l;
      int tok = e4 >> 5, k4 = (e4 & 31) << 2;
      int a = a0 + (tok >> 3), t = t0 + (tok & 7);
      us4 au = *(const us4*)&agentpb[((size_t)b * NAG + a) * MH + k4];
      us4 tu = *(const us4*)&attnpb[((size_t)b * TT + t) * MH + k4];
      float4 bb = *(const float4*)&b1g[k4];
      float x0 = b2f(au[0]) + b2f(tu[0]) + bb.x;
      float x1 = b2f(au[1]) + b2f(tu[1]) + bb.y;
      float x2 = b2f(au[2]) + b2f(tu[2]) + bb.z;
      float x3 = b2f(au[3]) + b2f(tu[3]) + bb.w;
      *(us4*)&Xb[tok][k4] = pack4(x0 * rcpf(1.f + __expf(-x0)),
                                  x1 * rcpf(1.f + __expf(-x1)),
                                  x2 * rcpf(1.f + __expf(-x2)),
                                  x3 * rcpf(1.f + __expf(-x3)));
    }
    __syncthreads();
    f32x4 acc[8] = {zero, zero, zero, zero, zero, zero, zero, zero};
    #pragma unroll
    for (int k0 = 0; k0 < MH; k0 += 32) {
      short8 af = *(const short8*)&Xb[(w << 4) + lcol][k0 + kgrp];
      #pragma unroll
      for (int tc = 0; tc < 8; ++tc) {
        short8 bfr = *(const short8*)&Wb[(tc << 4) + lcol][k0 + kgrp];
        acc[tc] = __builtin_amdgcn_mfma_f32_16x16x32_bf16(af, bfr, acc[tc], 0, 0, 0);
      }
    }
    float psum[4] = {0.f, 0.f, 0.f, 0.f};
    #pragma unroll
    for (int tc = 0; tc < 8; ++tc) {
      int o = (tc << 4) + lcol;
      float b2o = b2g[o], w3o = w3[o];
      #pragma unroll
      for (int r = 0; r < 4; ++r) {
        float hv = acc[tc][r] + b2o;
        hv = hv * rcpf(1.f + __expf(-hv));
        psum[r] += hv * w3o;
      }
    }
    #pragma unroll
    for (int r = 0; r < 4; ++r) {
      float p = psum[r];
      p += __shfl_xor(p, 1); p += __shfl_xor(p, 2);
      p += __shfl_xor(p, 4); p += __shfl_xor(p, 8);
      if (lcol == 0) {
        int tok = (w << 4) + (lgrp << 2) + r;
        int a = a0 + (tok >> 3), t = t0 + (tok & 7);
        float mask = rcpf(1.f + __expf(-(p + b3v)));
        size_t mi = ((size_t)b * NAG + a) * TT + t;
        mask_out[mi] = mask;
        emb_out[mi * 4 + 0] = (mask * m0 + e0) * es;
        emb_out[mi * 4 + 1] = (mask * m1 + e1) * es;
        emb_out[mi * 4 + 2] = (mask * m2 + e2) * es;
        emb_out[mi * 4 + 3] = (mask * m3 + e3) * es;
      }
    }
  }
}

extern "C" void kernel_launch(void* const* d_in, const int* in_sizes, int n_in,
                              void* d_out, int out_size, void* d_ws, size_t ws_size,
                              hipStream_t stream) {
  const float* context = (const float*)d_in[0];
  const float* agent   = (const float*)d_in[1];
  const float* temb    = (const float*)d_in[2];
  const float* tw      = (const float*)d_in[3];
  const float* tb      = (const float*)d_in[4];
  const float* inw     = (const float*)d_in[5];
  const float* inb     = (const float*)d_in[6];
  const float* outw    = (const float*)d_in[7];
  const float* outb    = (const float*)d_in[8];
  const float* w1      = (const float*)d_in[9];
  const float* b1      = (const float*)d_in[10];
  const float* w2      = (const float*)d_in[11];
  const float* b2      = (const float*)d_in[12];
  const float* w3      = (const float*)d_in[13];
  const float* b3      = (const float*)d_in[14];
  const float* mew     = (const float*)d_in[15];
  const float* meb     = (const float*)d_in[16];
  const float* esc     = (const float*)d_in[17];

  float* ws = (float*)d_ws;
  float* bf  = ws + 0;                 // 128
  float* oP  = ws + 128;               // 2*655360
  float* lP  = ws + 1310848;           // 2*20480
  ushort* u16 = (ushort*)(ws + 1351808);
  ushort* wfb     = u16;               // 32768
  ushort* agentpb = u16 + 32768;       // 262144
  ushort* attnpb  = u16 + 294912;      // 327680
  ushort* kbufb   = u16 + 622592;      // 4194304
  ushort* vbufb   = u16 + 4816896;     // 4194304
  ushort* qb      = u16 + 9011200;     // 20480

  float* mask_out = (float*)d_out;
  float* emb_out  = mask_out + (size_t)BB * NAG * TT;

  k_P<<<dim3(196 + 1024), dim3(256), 0, stream>>>(
      temb, tw, tb, inw, inb, w1, outw, outb, agent, context,
      qb, wfb, bf, agentpb, kbufb, vbufb);
  k_B<<<dim3(512), dim3(256), 0, stream>>>(
      qb, kbufb, vbufb, oP, lP);
  k_C<<<dim3(80), dim3(256), 0, stream>>>(oP, lP, wfb, bf, attnpb);
  k_D<<<dim3(5, 8, 32), dim3(256), 0, stream>>>(
      agentpb, attnpb, w2, b1, b2, w3, b3, mew, meb, esc, mask_out, emb_out);
}

// Round 23
// 66.589 us; speedup vs baseline: 1.1567x; 1.1175x over previous
//
#include <hip/hip_runtime.h>
#include <hip/hip_bf16.h>
#include <math.h>

#define BB 32
#define NCTX 512
#define NAG 64
#define DD 256
#define TT 80
#define TEMB 64
#define NH 8
#define HD 32
#define MH 128

// d_out is FLOAT32: mask [0,163840) then emb [163840,819200).
// Validator bf16(RNE)-casts both sides. (Established rounds 0-8.)

typedef __attribute__((ext_vector_type(8))) short short8;
typedef __attribute__((ext_vector_type(4))) float f32x4;
typedef __attribute__((ext_vector_type(4))) unsigned short us4;

static __device__ inline ushort f2b(float f) {
  __hip_bfloat16 h = __float2bfloat16(f);
  return *reinterpret_cast<const ushort*>(&h);
}
static __device__ inline float b2f(ushort u) {
  __hip_bfloat16 h = *reinterpret_cast<const __hip_bfloat16*>(&u);
  return __bfloat162float(h);
}
static __device__ inline us4 pack4(float a, float b, float c, float d) {
  us4 r = {f2b(a), f2b(b), f2b(c), f2b(d)};
  return r;
}
static __device__ inline float rcpf(float x) { return __builtin_amdgcn_rcpf(x); }

#define OPART 655360   // floats per o-partial  (256 bh * 80 t * 32 d)
#define LPART 20480    // floats per l-partial  (256 bh * 80 t)

// ---- P: qproj-MFMA(4) | fusew(128) | agent-gemm(64) | KV proj (1024)
//  KV epilogue: transpose-through-LDS -> coalesced stores (was 2B scatter).
__global__ __launch_bounds__(256, 4) void k_P(
    const float* __restrict__ temb, const float* __restrict__ tw,
    const float* __restrict__ tb, const float* __restrict__ inw,
    const float* __restrict__ inb, const float* __restrict__ w1,
    const float* __restrict__ outw, const float* __restrict__ outb,
    const float* __restrict__ agent, const float* __restrict__ context,
    ushort* __restrict__ qb, ushort* __restrict__ wfb, float* __restrict__ bf,
    ushort* __restrict__ agentpb,
    ushort* __restrict__ kb, ushort* __restrict__ vb) {
  __shared__ __align__(16) char sm[30976];
  const int blk = blockIdx.x;
  const int tid = threadIdx.x;
  const int w = tid >> 6, lane = tid & 63;
  const int lgrp = lane >> 4, lcol = lane & 15;
  const int kgrp = lgrp << 3;
  f32x4 zero = {0.f, 0.f, 0.f, 0.f};

  if (blk < 4) {
    // ---- qproj. Phase 1: q_in = temb@tw^T (acc in regs), tw in 2 halves.
    ushort (*Tb)[72]   = (ushort(*)[72])sm;             // [80][72]  11520
    ushort (*Twin)[72] = (ushort(*)[72])(sm + 11520);   // [128][72] 18432
    ushort (*Qs)[136]  = (ushort(*)[136])sm;            // [80][136] 21760 (alias)
    ushort (*Bq)[72]   = (ushort(*)[72])(sm + 21760);   // [64][72]   9216
    #pragma unroll
    for (int l = 0; l < 5; ++l) {
      int e4 = tid + 256 * l;
      if (e4 < 1280) {
        int t = e4 >> 4, k4 = (e4 & 15) << 2;
        float4 v = *(const float4*)&temb[t * TEMB + k4];
        *(us4*)&Tb[t][k4] = pack4(v.x, v.y, v.z, v.w);
      }
    }
    f32x4 qin[2][5][2];
    #pragma unroll
    for (int hf = 0; hf < 2; ++hf)
      #pragma unroll
      for (int mt = 0; mt < 5; ++mt)
        #pragma unroll
        for (int nt = 0; nt < 2; ++nt) qin[hf][mt][nt] = zero;
    for (int hf = 0; hf < 2; ++hf) {
      __syncthreads();   // Tb staged (hf=0) / prior Twin reads done (hf=1)
      #pragma unroll
      for (int l = 0; l < 8; ++l) {
        int e4 = tid + 256 * l;      // 2048 quads
        int r = e4 >> 4, k4 = (e4 & 15) << 2;
        float4 v = *(const float4*)&tw[(size_t)((hf << 7) + r) * TEMB + k4];
        *(us4*)&Twin[r][k4] = pack4(v.x, v.y, v.z, v.w);
      }
      __syncthreads();
      #pragma unroll
      for (int ks = 0; ks < 2; ++ks) {
        #pragma unroll
        for (int mt = 0; mt < 5; ++mt) {
          short8 af = *(const short8*)&Tb[(mt << 4) + lcol][(ks << 5) + kgrp];
          #pragma unroll
          for (int nt = 0; nt < 2; ++nt) {
            short8 bfr = *(const short8*)&Twin[(w << 5) + (nt << 4) + lcol][(ks << 5) + kgrp];
            qin[hf][mt][nt] = __builtin_amdgcn_mfma_f32_16x16x32_bf16(af, bfr, qin[hf][mt][nt], 0, 0, 0);
          }
        }
      }
    }
    // Phase 2: q = q_in@wq^T + bq, scaled; Qs written per 128-col half.
    const int n0q = blk << 6;
    f32x4 acc2[5] = {zero, zero, zero, zero, zero};
    for (int kh = 0; kh < 2; ++kh) {
      __syncthreads();   // phase-1 LDS reads done / prior Qs+Bq reads done
      #pragma unroll
      for (int nt = 0; nt < 2; ++nt) {
        int n = (kh << 7) + (w << 5) + (nt << 4) + lcol;
        float tbn = tb[n];
        int c = (w << 5) + (nt << 4) + lcol;
        #pragma unroll
        for (int mt = 0; mt < 5; ++mt)
          #pragma unroll
          for (int r = 0; r < 4; ++r)
            Qs[(mt << 4) + (lgrp << 2) + r][c] = f2b(qin[kh][mt][nt][r] + tbn);
      }
      __syncthreads();
      for (int kc = 0; kc < 2; ++kc) {
        #pragma unroll
        for (int l = 0; l < 4; ++l) {
          int e4 = tid + 256 * l;    // 1024 quads
          int n = e4 >> 4, k4 = (e4 & 15) << 2;
          float4 v = *(const float4*)&inw[(size_t)(n0q + n) * DD + (kh << 7) + (kc << 6) + k4];
          *(us4*)&Bq[n][k4] = pack4(v.x, v.y, v.z, v.w);
        }
        __syncthreads();
        #pragma unroll
        for (int ks = 0; ks < 2; ++ks) {
          short8 bfr = *(const short8*)&Bq[(w << 4) + lcol][(ks << 5) + kgrp];
          #pragma unroll
          for (int mt = 0; mt < 5; ++mt) {
            short8 af = *(const short8*)&Qs[(mt << 4) + lcol][(kc << 6) + (ks << 5) + kgrp];
            acc2[mt] = __builtin_amdgcn_mfma_f32_16x16x32_bf16(af, bfr, acc2[mt], 0, 0, 0);
          }
        }
        __syncthreads();   // Bq reuse
      }
    }
    int n = n0q + (w << 4) + lcol;
    float bn = inb[n];
    #pragma unroll
    for (int mt = 0; mt < 5; ++mt)
      #pragma unroll
      for (int r = 0; r < 4; ++r) {
        int m = (mt << 4) + (lgrp << 2) + r;
        qb[m * DD + n] = f2b((acc2[mt][r] + bn) * 0.17677669529663687f);
      }
  } else if (blk < 132) {
    int i = blk - 4, j = tid;
    float* w1row = (float*)sm;
    float* red   = (float*)(sm + 1024);
    w1row[j] = w1[i * 2 * DD + DD + j];
    __syncthreads();
    float acc = 0.f;
    for (int k = 0; k < DD; ++k) acc += w1row[k] * outw[k * DD + j];
    wfb[i * DD + j] = f2b(acc);
    red[j] = w1row[j] * outb[j];
    __syncthreads();
    for (int s2 = 128; s2 > 0; s2 >>= 1) {
      if (j < s2) red[j] += red[j + s2];
      __syncthreads();
    }
    if (j == 0) bf[i] = red[0];
  } else if (blk < 196) {
    // agent projection: dual fp32-staged 64x64 GEMM, out bf16 agentpb
    int gb = blk - 132;
    const int m0 = (gb >> 1) << 6;
    const int n0 = (gb & 1) << 6;
    ushort (*Ab)[72] = (ushort(*)[72])sm;
    ushort (*Bb)[72] = (ushort(*)[72])(sm + 9216);
    f32x4 acc[4] = {zero, zero, zero, zero};
    for (int k0 = 0; k0 < 256; k0 += 64) {
      __syncthreads();
      #pragma unroll
      for (int l = 0; l < 4; ++l) {
        int e = tid + 256 * l;
        int m = e >> 4, k4 = (e & 15) << 2;
        float4 va = *(const float4*)&agent[(size_t)(m0 + m) * 256 + k0 + k4];
        *(us4*)&Ab[m][k4] = pack4(va.x, va.y, va.z, va.w);
        float4 vb2 = *(const float4*)&w1[(size_t)(n0 + m) * 512 + k0 + k4];
        *(us4*)&Bb[m][k4] = pack4(vb2.x, vb2.y, vb2.z, vb2.w);
      }
      __syncthreads();
      #pragma unroll
      for (int kk = 0; kk < 64; kk += 32) {
        short8 af = *(const short8*)&Ab[(w << 4) + lcol][kk + kgrp];
        #pragma unroll
        for (int tc = 0; tc < 4; ++tc) {
          short8 bfr = *(const short8*)&Bb[(tc << 4) + lcol][kk + kgrp];
          acc[tc] = __builtin_amdgcn_mfma_f32_16x16x32_bf16(af, bfr, acc[tc], 0, 0, 0);
        }
      }
    }
    #pragma unroll
    for (int tc = 0; tc < 4; ++tc) {
      int n = n0 + (tc << 4) + lcol;
      #pragma unroll
      for (int r = 0; r < 4; ++r) {
        int m = m0 + (w << 4) + (lgrp << 2) + r;
        agentpb[(size_t)m * MH + n] = f2b(acc[tc][r]);
      }
    }
  } else {
    // KV proj: 64(M) x 128(N) tile, fp32 inputs, pack staging.
    // Each block is purely-K (n0<256) or purely-V (n0>=256).
    int kb2 = blk - 196;
    const int m0 = (kb2 & 255) << 6;
    const int n0 = (kb2 >> 8) << 7;
    const int bl = m0 >> 9, s0 = m0 & 511;
    ushort (*Ab)[72] = (ushort(*)[72])sm;
    ushort (*Bb)[72] = (ushort(*)[72])(sm + 9216);
    const float* Wm = inw + 256 * 256;
    const float* bkv = inb + 256;
    f32x4 acc[8];
    #pragma unroll
    for (int tc = 0; tc < 8; ++tc) acc[tc] = zero;
    for (int k0 = 0; k0 < 256; k0 += 64) {
      __syncthreads();
      #pragma unroll
      for (int l = 0; l < 4; ++l) {
        int e = tid + 256 * l;
        int m = e >> 4, k4 = (e & 15) << 2;
        float4 v = *(const float4*)&context[(size_t)(m0 + m) * 256 + k0 + k4];
        *(us4*)&Ab[m][k4] = pack4(v.x, v.y, v.z, v.w);
      }
      #pragma unroll
      for (int l = 0; l < 8; ++l) {
        int e = tid + 256 * l;
        int n = e >> 4, k4 = (e & 15) << 2;
        float4 v = *(const float4*)&Wm[(size_t)(n0 + n) * 256 + k0 + k4];
        *(us4*)&Bb[n][k4] = pack4(v.x, v.y, v.z, v.w);
      }
      __syncthreads();
      #pragma unroll
      for (int kk = 0; kk < 64; kk += 32) {
        short8 af = *(const short8*)&Ab[(w << 4) + lcol][kk + kgrp];
        #pragma unroll
        for (int tc = 0; tc < 8; ++tc) {
          short8 bfr = *(const short8*)&Bb[(tc << 4) + lcol][kk + kgrp];
          acc[tc] = __builtin_amdgcn_mfma_f32_16x16x32_bf16(af, bfr, acc[tc], 0, 0, 0);
        }
      }
    }
    // ---- epilogue: transpose-through-LDS (alias Ab/Bb), coalesced stores
    __syncthreads();   // all Ab/Bb reads complete before aliasing
    if (n0 < 256) {
      // K: stage [64 s][128 n] (pad->136), store 16B row-chunks
      ushort (*Kt)[136] = (ushort(*)[136])sm;   // 17408 B
      #pragma unroll
      for (int tc = 0; tc < 8; ++tc) {
        int nloc = (tc << 4) + lcol;
        float bias = bkv[n0 + nloc];
        #pragma unroll
        for (int r = 0; r < 4; ++r) {
          int sloc = (w << 4) + (lgrp << 2) + r;
          Kt[sloc][nloc] = f2b(acc[tc][r] + bias);
        }
      }
      __syncthreads();
      #pragma unroll
      for (int l = 0; l < 4; ++l) {
        int e = tid + 256 * l;          // 1024 short8 units
        int sloc = e >> 4, u = e & 15;
        int n = n0 + (u << 3);
        int h = n >> 5, hd = n & 31;
        short8 vv = *(const short8*)&Kt[sloc][u << 3];
        *(short8*)&kb[(((size_t)(bl * NH + h)) * NCTX + s0 + sloc) * HD + hd] = vv;
      }
    } else {
      // V: stage [128 n][64 s] (pad->68), store 8B contiguous-s chunks
      ushort (*Vt)[68] = (ushort(*)[68])sm;     // 17408 B
      #pragma unroll
      for (int tc = 0; tc < 8; ++tc) {
        int nloc = (tc << 4) + lcol;
        float bias = bkv[n0 + nloc];
        #pragma unroll
        for (int r = 0; r < 4; ++r) {
          int sloc = (w << 4) + (lgrp << 2) + r;
          Vt[nloc][sloc] = f2b(acc[tc][r] + bias);
        }
      }
      __syncthreads();
      #pragma unroll
      for (int l = 0; l < 8; ++l) {
        int e = tid + 256 * l;          // 2048 uint2 (8B) units
        int nloc = e >> 4, s4 = (e & 15) << 2;
        int n = n0 + nloc;
        int h = (n >> 5) & 7, hd = n & 31;
        uint2 vv = *(const uint2*)&Vt[nloc][s4];
        *(uint2*)&vb[(((size_t)(bl * NH + h)) * HD + hd) * NCTX + s0 + s4] = vv;
      }
    }
  }
}

// ---- B: attention halves. 512 blocks: (bh, part). Each does 256 s-positions
// (2 chunks of 128), writes PARTIAL o (fp32) and l to ws.
__global__ __launch_bounds__(256) void k_B(
    const ushort* __restrict__ qb, const ushort* __restrict__ kg,
    const ushort* __restrict__ vtg, float* __restrict__ oP,
    float* __restrict__ lP) {
  __shared__ __align__(16) char sm[47104];
  ushort (*Qb)[40]  = (ushort(*)[40])(sm);
  ushort (*Kb)[40]  = (ushort(*)[40])(sm + 6400);
  ushort (*Vb)[136] = (ushort(*)[136])(sm + 16640);
  ushort (*Pb)[136] = (ushort(*)[136])(sm + 25344);
  float  (*Ored)[80][32] = (float(*)[80][32])(sm);
  float  (*lred)[80] = (float(*)[80])(sm + 40960);
  const int blk = blockIdx.x;
  const int bhl = blk >> 1, part = blk & 1;
  const int h = bhl & 7;
  const int tid = threadIdx.x;
  const int w = tid >> 6, lane = tid & 63;
  const int lgrp = lane >> 4, lcol = lane & 15;
  const int kgrp = lgrp << 3;
  const ushort* kp = kg + (size_t)bhl * NCTX * HD;
  const ushort* vp = vtg + (size_t)bhl * HD * NCTX;
  #pragma unroll
  for (int l = 0; l < 2; ++l) {
    int e = tid + 256 * l;        // 320 short8 copies of Q (bf16 in global)
    if (e < 320) {
      int t = e >> 2, d8 = (e & 3) << 3;
      *(short8*)&Qb[t][d8] = *(const short8*)&qb[t * DD + h * HD + d8];
    }
  }
  f32x4 zero = {0.f, 0.f, 0.f, 0.f};
  f32x4 oacc[5][2];
  #pragma unroll
  for (int tt = 0; tt < 5; ++tt) { oacc[tt][0] = zero; oacc[tt][1] = zero; }
  float lpart[5] = {0.f, 0.f, 0.f, 0.f, 0.f};
  for (int c = 0; c < 2; ++c) {
    const int s0 = part * 256 + c * 128;
    __syncthreads();
    #pragma unroll
    for (int l = 0; l < 2; ++l) {
      int e = tid + 256 * l;
      int sl = e >> 2, d8 = (e & 3) << 3;
      *(short8*)&Kb[sl][d8] = *(const short8*)&kp[(size_t)(s0 + sl) * HD + d8];
      int d = e >> 4, s8 = (e & 15) << 3;
      *(short8*)&Vb[d][s8] = *(const short8*)&vp[(size_t)d * NCTX + s0 + s8];
    }
    __syncthreads();
    f32x4 sacc[2][5];
    #pragma unroll
    for (int st = 0; st < 2; ++st) {
      short8 af = *(const short8*)&Kb[(w << 5) + (st << 4) + lcol][kgrp];
      #pragma unroll
      for (int tt = 0; tt < 5; ++tt) {
        short8 bfr = *(const short8*)&Qb[(tt << 4) + lcol][kgrp];
        sacc[st][tt] = __builtin_amdgcn_mfma_f32_16x16x32_bf16(af, bfr, zero, 0, 0, 0);
      }
    }
    #pragma unroll
    for (int st = 0; st < 2; ++st) {
      #pragma unroll
      for (int tt = 0; tt < 5; ++tt) {
        float p0 = __expf(sacc[st][tt][0]), p1 = __expf(sacc[st][tt][1]);
        float p2 = __expf(sacc[st][tt][2]), p3 = __expf(sacc[st][tt][3]);
        ushort u0 = f2b(p0), u1 = f2b(p1), u2 = f2b(p2), u3 = f2b(p3);
        lpart[tt] += b2f(u0) + b2f(u1) + b2f(u2) + b2f(u3);
        uint2 pk;
        pk.x = (uint)u0 | ((uint)u1 << 16);
        pk.y = (uint)u2 | ((uint)u3 << 16);
        *(uint2*)&Pb[(tt << 4) + lcol][(w << 5) + (st << 4) + (lgrp << 2)] = pk;
      }
    }
    __syncthreads();
    #pragma unroll
    for (int tt = 0; tt < 5; ++tt) {
      short8 pa = *(const short8*)&Pb[(tt << 4) + lcol][(w << 5) + kgrp];
      #pragma unroll
      for (int dt = 0; dt < 2; ++dt) {
        short8 vbr = *(const short8*)&Vb[(dt << 4) + lcol][(w << 5) + kgrp];
        oacc[tt][dt] = __builtin_amdgcn_mfma_f32_16x16x32_bf16(pa, vbr, oacc[tt][dt], 0, 0, 0);
      }
    }
  }
  __syncthreads();
  #pragma unroll
  for (int tt = 0; tt < 5; ++tt) {
    float l = lpart[tt];
    l += __shfl_xor(l, 16); l += __shfl_xor(l, 32);
    if (lane < 16) lred[w][(tt << 4) + lane] = l;
    #pragma unroll
    for (int dt = 0; dt < 2; ++dt)
      #pragma unroll
      for (int r = 0; r < 4; ++r)
        Ored[w][(tt << 4) + (lgrp << 2) + r][(dt << 4) + lcol] = oacc[tt][dt][r];
  }
  __syncthreads();
  float* op = oP + (size_t)part * OPART + (size_t)bhl * TT * HD;
  for (int i = tid; i < TT * HD; i += 256) {
    int t = i >> 5, d = i & 31;
    op[i] = Ored[0][t][d] + Ored[1][t][d] + Ored[2][t][d] + Ored[3][t][d];
  }
  for (int t = tid; t < TT; t += 256)
    lP[(size_t)part * LPART + (size_t)bhl * TT + t] =
        lred[0][t] + lred[1][t] + lred[2][t] + lred[3][t];
}

// ---- C: combine attention partials + attn-out projection (80 blocks)
__global__ __launch_bounds__(256) void k_C(
    const float* __restrict__ oP, const float* __restrict__ lP,
    const ushort* __restrict__ wfb, const float* __restrict__ bfv,
    ushort* __restrict__ attnpb) {
  __shared__ __align__(16) ushort Ab[64][72];
  const int gb = blockIdx.x;
  const int m0 = (gb >> 1) << 6;
  const int n0 = (gb & 1) << 6;
  const int tid = threadIdx.x;
  const int w = tid >> 6, lane = tid & 63;
  const int lgrp = lane >> 4, lcol = lane & 15;
  const int kgrp = lgrp << 3;
  f32x4 zero = {0.f, 0.f, 0.f, 0.f};
  f32x4 acc[4] = {zero, zero, zero, zero};
  for (int k0 = 0; k0 < 256; k0 += 64) {
    __syncthreads();
    #pragma unroll
    for (int l = 0; l < 4; ++l) {
      int e = tid + 256 * l;
      int m = e >> 4, c4 = (e & 15) << 2;
      int row = m0 + m;
      int bg = row / 80, t = row - bg * 80;
      int dfull = k0 + c4, h = dfull >> 5, hd = dfull & 31;
      size_t bh = (size_t)(bg * NH + h);
      const float* o0 = &oP[(bh * TT + t) * HD + hd];
      float4 a0 = *(const float4*)o0;
      float4 a1 = *(const float4*)(o0 + OPART);
      float li = rcpf(lP[bh * TT + t] + lP[LPART + bh * TT + t]);
      *(us4*)&Ab[m][c4] = pack4((a0.x + a1.x) * li, (a0.y + a1.y) * li,
                                (a0.z + a1.z) * li, (a0.w + a1.w) * li);
    }
    __syncthreads();
    #pragma unroll
    for (int kk = 0; kk < 64; kk += 32) {
      short8 af = *(const short8*)&Ab[(w << 4) + lcol][kk + kgrp];
      #pragma unroll
      for (int tc = 0; tc < 4; ++tc) {
        short8 bfr = *(const short8*)&wfb[(size_t)(n0 + (tc << 4) + lcol) * 256 + k0 + kk + kgrp];
        acc[tc] = __builtin_amdgcn_mfma_f32_16x16x32_bf16(af, bfr, acc[tc], 0, 0, 0);
      }
    }
  }
  #pragma unroll
  for (int tc = 0; tc < 4; ++tc) {
    int n = n0 + (tc << 4) + lcol;
    float bv = bfv[n];
    #pragma unroll
    for (int r = 0; r < 4; ++r) {
      int m = m0 + (w << 4) + (lgrp << 2) + r;
      attnpb[(size_t)m * MH + n] = f2b(acc[tc][r] + bv);
    }
  }
}

// ---- D: fused MLP. 2 token-tiles per block reusing staged W2 (from fp32).
__global__ __launch_bounds__(256) void k_D(
    const ushort* __restrict__ agentpb, const ushort* __restrict__ attnpb,
    const float* __restrict__ w2, const float* __restrict__ b1g,
    const float* __restrict__ b2g, const float* __restrict__ w3,
    const float* __restrict__ b3, const float* __restrict__ mew,
    const float* __restrict__ meb, const float* __restrict__ esc,
    float* __restrict__ mask_out, float* __restrict__ emb_out) {
  const int a0 = blockIdx.y * 8;
  const int b = blockIdx.z;
  const int tid = threadIdx.x;
  __shared__ ushort Xb[64][136];
  __shared__ ushort Wb[128][136];
  #pragma unroll
  for (int l = 0; l < 16; ++l) {
    int e4 = tid + 256 * l;
    int o = e4 >> 5, k4 = (e4 & 31) << 2;
    float4 v = *(const float4*)&w2[(size_t)o * MH + k4];
    *(us4*)&Wb[o][k4] = pack4(v.x, v.y, v.z, v.w);
  }
  const int w = tid >> 6, lane = tid & 63;
  const int lgrp = lane >> 4, lcol = lane & 15;
  const int kgrp = lgrp << 3;
  f32x4 zero = {0.f, 0.f, 0.f, 0.f};
  float es = esc[0], b3v = b3[0];
  float m0 = mew[0], m1 = mew[1], m2 = mew[2], m3 = mew[3];
  float e0 = meb[0], e1 = meb[1], e2 = meb[2], e3 = meb[3];
  for (int rep = 0; rep < 2; ++rep) {
    const int t0 = blockIdx.x * 16 + rep * 8;
    __syncthreads();   // Wb ready (rep0) / previous Xb reads done (rep1)
    #pragma unroll
    for (int l = 0; l < 8; ++l) {
      int e4 = tid + 256 * l;
      int tok = e4 >> 5, k4 = (e4 & 31) << 2;
      int a = a0 + (tok >> 3), t = t0 + (tok & 7);
      us4 au = *(const us4*)&agentpb[((size_t)b * NAG + a) * MH + k4];
      us4 tu = *(const us4*)&attnpb[((size_t)b * TT + t) * MH + k4];
      float4 bb = *(const float4*)&b1g[k4];
      float x0 = b2f(au[0]) + b2f(tu[0]) + bb.x;
      float x1 = b2f(au[1]) + b2f(tu[1]) + bb.y;
      float x2 = b2f(au[2]) + b2f(tu[2]) + bb.z;
      float x3 = b2f(au[3]) + b2f(tu[3]) + bb.w;
      *(us4*)&Xb[tok][k4] = pack4(x0 * rcpf(1.f + __expf(-x0)),
                                  x1 * rcpf(1.f + __expf(-x1)),
                                  x2 * rcpf(1.f + __expf(-x2)),
                                  x3 * rcpf(1.f + __expf(-x3)));
    }
    __syncthreads();
    f32x4 acc[8] = {zero, zero, zero, zero, zero, zero, zero, zero};
    #pragma unroll
    for (int k0 = 0; k0 < MH; k0 += 32) {
      short8 af = *(const short8*)&Xb[(w << 4) + lcol][k0 + kgrp];
      #pragma unroll
      for (int tc = 0; tc < 8; ++tc) {
        short8 bfr = *(const short8*)&Wb[(tc << 4) + lcol][k0 + kgrp];
        acc[tc] = __builtin_amdgcn_mfma_f32_16x16x32_bf16(af, bfr, acc[tc], 0, 0, 0);
      }
    }
    float psum[4] = {0.f, 0.f, 0.f, 0.f};
    #pragma unroll
    for (int tc = 0; tc < 8; ++tc) {
      int o = (tc << 4) + lcol;
      float b2o = b2g[o], w3o = w3[o];
      #pragma unroll
      for (int r = 0; r < 4; ++r) {
        float hv = acc[tc][r] + b2o;
        hv = hv * rcpf(1.f + __expf(-hv));
        psum[r] += hv * w3o;
      }
    }
    #pragma unroll
    for (int r = 0; r < 4; ++r) {
      float p = psum[r];
      p += __shfl_xor(p, 1); p += __shfl_xor(p, 2);
      p += __shfl_xor(p, 4); p += __shfl_xor(p, 8);
      if (lcol == 0) {
        int tok = (w << 4) + (lgrp << 2) + r;
        int a = a0 + (tok >> 3), t = t0 + (tok & 7);
        float mask = rcpf(1.f + __expf(-(p + b3v)));
        size_t mi = ((size_t)b * NAG + a) * TT + t;
        mask_out[mi] = mask;
        emb_out[mi * 4 + 0] = (mask * m0 + e0) * es;
        emb_out[mi * 4 + 1] = (mask * m1 + e1) * es;
        emb_out[mi * 4 + 2] = (mask * m2 + e2) * es;
        emb_out[mi * 4 + 3] = (mask * m3 + e3) * es;
      }
    }
  }
}

extern "C" void kernel_launch(void* const* d_in, const int* in_sizes, int n_in,
                              void* d_out, int out_size, void* d_ws, size_t ws_size,
                              hipStream_t stream) {
  const float* context = (const float*)d_in[0];
  const float* agent   = (const float*)d_in[1];
  const float* temb    = (const float*)d_in[2];
  const float* tw      = (const float*)d_in[3];
  const float* tb      = (const float*)d_in[4];
  const float* inw     = (const float*)d_in[5];
  const float* inb     = (const float*)d_in[6];
  const float* outw    = (const float*)d_in[7];
  const float* outb    = (const float*)d_in[8];
  const float* w1      = (const float*)d_in[9];
  const float* b1      = (const float*)d_in[10];
  const float* w2      = (const float*)d_in[11];
  const float* b2      = (const float*)d_in[12];
  const float* w3      = (const float*)d_in[13];
  const float* b3      = (const float*)d_in[14];
  const float* mew     = (const float*)d_in[15];
  const float* meb     = (const float*)d_in[16];
  const float* esc     = (const float*)d_in[17];

  float* ws = (float*)d_ws;
  float* bf  = ws + 0;                 // 128
  float* oP  = ws + 128;               // 2*655360
  float* lP  = ws + 1310848;           // 2*20480
  ushort* u16 = (ushort*)(ws + 1351808);
  ushort* wfb     = u16;               // 32768
  ushort* agentpb = u16 + 32768;       // 262144
  ushort* attnpb  = u16 + 294912;      // 327680
  ushort* kbufb   = u16 + 622592;      // 4194304
  ushort* vbufb   = u16 + 4816896;     // 4194304
  ushort* qb      = u16 + 9011200;     // 20480

  float* mask_out = (float*)d_out;
  float* emb_out  = mask_out + (size_t)BB * NAG * TT;

  k_P<<<dim3(196 + 1024), dim3(256), 0, stream>>>(
      temb, tw, tb, inw, inb, w1, outw, outb, agent, context,
      qb, wfb, bf, agentpb, kbufb, vbufb);
  k_B<<<dim3(512), dim3(256), 0, stream>>>(
      qb, kbufb, vbufb, oP, lP);
  k_C<<<dim3(80), dim3(256), 0, stream>>>(oP, lP, wfb, bf, attnpb);
  k_D<<<dim3(5, 8, 32), dim3(256), 0, stream>>>(
      agentpb, attnpb, w2, b1, b2, w3, b3, mew, meb, esc, mask_out, emb_out);
}